// Round 3
// baseline (606.242 us; speedup 1.0000x reference)
//
#include <hip/hip_runtime.h>

// IIR2DResidual: separable bidirectional first-order IIR (a = 0.5, mirror border)
// along W then H on (N=4, H=512, W=512, C=64) fp32 channels-last, then
// out = x + sigmoid(alpha[c]) * (y - x).
//
// R4 theory (post-mortem of R2/R3): arrays of ext_vector elements get demoted
// to scratch (R2: 192 live floats but VGPR=116; R3: 96 live but VGPR=72),
// while R0's plain scalar float window stayed register-resident (VGPR=100).
// So: keep the f2 (8 B/lane) global access pattern, but hold the window as
// TWO SCALAR float arrays. Loads: dwordx2 -> extractelement (free); stores:
// reassemble f2. This is the first variant with BOTH wide access and a
// register-resident window.
//
// Lane map: lane = channel pair (lane&31)*2 of line (lane>>5); wave covers
// 2 lines x 64 channels -> every global op is 2x256B (H) or 512B (V) dense.
//
// Chunking: T=32 outputs, K=8 warm-up halo (0.5^8 ~ 4e-3; measured absmax
// 1.6e-2 vs threshold 6.6e-2). Mirror init exact at w0=0 (warm-up predicated
// off); right edge holds yf[L-1] as fixpoint so the unconditional backward
// warm-up is exact.
//
// XCD swizzle: chunk-adjacent logical blocks land on the same XCD's L2 so
// halo re-reads hit (bijective; grid % 8 == 0 always).
//
// ws robustness: process images in groups sized to fit ws; if ws can't hold
// one image (64 MiB), fall back to in-place V-pass (no scratch needed).

typedef float f2 __attribute__((ext_vector_type(2)));

constexpr int Tc   = 32;            // output chunk per wave
constexpr int Kc   = 8;             // warm-up halo
constexpr int WIN  = Tc + 2 * Kc;   // 48 positions -> 96 scalar floats/lane
constexpr int L    = 512;           // scan length (H == W == 512)
constexpr int C    = 64;
constexpr int W    = 512;
constexpr int H    = 512;
constexpr int CHUNKS = L / Tc;      // 16

template<bool VERT, bool COMBINE>
__global__ __launch_bounds__(256)
void iir_scan(const float* __restrict__ in, float* __restrict__ out,
              const float* __restrict__ xres, const float* __restrict__ alpha)
{
    // --- XCD-aware bijective block swizzle (gridDim.x % 8 == 0 always) ---
    const int nb8 = (int)gridDim.x >> 3;
    const int bid = (int)blockIdx.x;
    const int lb  = (bid & 7) * nb8 + (bid >> 3);   // logical block id

    const int lane = threadIdx.x & 63;
    const int sub  = lane >> 5;          // which of 2 lines this lane serves
    const int c0   = (lane & 31) << 1;   // channel pair
    const int gw   = lb * 4 + (threadIdx.x >> 6);   // logical wave id
    const int lg   = gw >> 4;            // line-pair id (CHUNKS=16 chunks each)
    const int w0   = (gw & (CHUNKS - 1)) * Tc;

    const int n = lg >> 8;               // image index within launch group
    const int r = ((lg & 255) << 1) + sub;

    int base, stride;
    if (VERT) {
        // r = w; scan over h. One load instr = 2 adjacent w -> 512 B contiguous.
        base   = (n * H * W + r) * C + c0;
        stride = W * C;
    } else {
        // r = h; scan over w. One load instr = 2 rows x 256 B dense segments.
        base   = (n * H + r) * (W * C) + c0;
        stride = C;
    }
    const float* __restrict__ p = in + base;

    // Scalar window arrays (register-resident; see header comment).
    float va[WIN], vb[WIN];

    // --- load window (edge-clamped), 8 B/lane dwordx2 ---
#pragma unroll
    for (int j = 0; j < WIN; ++j) {
        int w = w0 - Kc + j;
        w = min(max(w, 0), L - 1);
        const f2 t = *(const f2*)(p + w * stride);
        va[j] = t.x;
        vb[j] = t.y;
    }

    // --- forward scan: yf[t] = 0.5*x[t] + 0.5*yf[t-1], mirror init ---
    float ca = va[0], cb = vb[0];        // = x[0] when w0 == 0 (exact mirror)
#pragma unroll
    for (int j = 0; j < WIN; ++j) {
        const int w = w0 - Kc + j;
        if (w >= 0 && w < L) {           // wave-uniform predicate
            ca = 0.5f * va[j] + 0.5f * ca;
            cb = 0.5f * vb[j] + 0.5f * cb;
        }
        va[j] = ca;                      // w >= L: hold yf[L-1] (fixpoint)
        vb[j] = cb;
    }

    // --- backward scan: yb[t] = 0.5*yf[t] + 0.5*yb[t+1] ---
    float c2a = va[WIN - 1], c2b = vb[WIN - 1];
#pragma unroll
    for (int j = WIN - 1; j >= Kc; --j) {
        c2a = 0.5f * va[j] + 0.5f * c2a;
        c2b = 0.5f * vb[j] + 0.5f * c2b;
        va[j] = c2a;
        vb[j] = c2b;
    }

    // --- store output region [w0, w0+Tc), 8 B/lane dwordx2 ---
    if (COMBINE) {
        const f2 av = *(const f2*)(alpha + c0);
        const float mixa = 1.0f / (1.0f + __expf(-av.x));
        const float mixb = 1.0f / (1.0f + __expf(-av.y));
#pragma unroll
        for (int j = Kc; j < Kc + Tc; ++j) {
            const int idx = base + (w0 + (j - Kc)) * stride;
            const f2 xv = *(const f2*)(xres + idx);
            f2 o;
            o.x = xv.x + mixa * (va[j] - xv.x);
            o.y = xv.y + mixb * (vb[j] - xv.y);
            *(f2*)(out + idx) = o;
        }
    } else {
#pragma unroll
        for (int j = Kc; j < Kc + Tc; ++j) {
            const int idx = base + (w0 + (j - Kc)) * stride;
            f2 o;
            o.x = va[j];
            o.y = vb[j];
            *(f2*)(out + idx) = o;
        }
    }
}

// Emergency V-pass when ws can't hold even one image: in-place on y (the
// H-pass result already in d_out). One wave owns 2 (n,w) lines x 32 channel
// pairs -> reads/writes only its own indices, race-free, zero scratch.
__global__ __launch_bounds__(256)
void iir_vpass_inplace(float* __restrict__ y, const float* __restrict__ xres,
                       const float* __restrict__ alpha)
{
    const int lane = threadIdx.x & 63;
    const int sub  = lane >> 5;
    const int c0   = (lane & 31) << 1;
    const int lg   = blockIdx.x * 4 + (threadIdx.x >> 6);  // [0, N*W/2)
    const int n = lg >> 8;
    const int w = ((lg & 255) << 1) + sub;
    const int base   = (n * H * W + w) * C + c0;
    const int stride = W * C;

    // forward, in place
    f2 carry = *(const f2*)(y + base);   // mirror init
    for (int h = 0; h < H; ++h) {
        const int idx = base + h * stride;
        f2 cur = *(const f2*)(y + idx);
        carry = 0.5f * cur + 0.5f * carry;
        *(f2*)(y + idx) = carry;
    }
    // backward + residual, in place
    const f2 av = *(const f2*)(alpha + c0);
    f2 mix;
#pragma unroll
    for (int q = 0; q < 2; ++q)
        mix[q] = 1.0f / (1.0f + __expf(-av[q]));
    f2 c2 = *(const f2*)(y + base + (H - 1) * stride);
    for (int h = H - 1; h >= 0; --h) {
        const int idx = base + h * stride;
        f2 cur = *(const f2*)(y + idx);
        c2 = 0.5f * cur + 0.5f * c2;
        const f2 xv = *(const f2*)(xres + idx);
        *(f2*)(y + idx) = xv + mix * (c2 - xv);
    }
}

extern "C" void kernel_launch(void* const* d_in, const int* in_sizes, int n_in,
                              void* d_out, int out_size, void* d_ws, size_t ws_size,
                              hipStream_t stream) {
    const float* x     = (const float*)d_in[0];
    const float* alpha = (const float*)d_in[1];
    float* out = (float*)d_out;
    float* t   = (float*)d_ws;

    const size_t imgElems = (size_t)H * W * C;          // 16,777,216
    const size_t imgBytes = imgElems * sizeof(float);   // 64 MiB
    const int    N        = 4;

    int g = (int)(ws_size / imgBytes);   // images that fit in ws
    if (g > N) g = N;

    if (g >= 1) {
        // Process images in groups of g: H-pass (x->ws), V-pass+combine (ws->out).
        for (int i0 = 0; i0 < N; i0 += g) {
            const int ni = (i0 + g <= N) ? g : (N - i0);
            const size_t off = (size_t)i0 * imgElems;
            // waves = ni*(512/2) line-pairs * 16 chunks; 4 waves/block
            // blocks = ni*1024 (always % 8 == 0 -> swizzle bijective)
            const dim3 grid((unsigned)(ni * 1024)), block(256);
            iir_scan<false, false><<<grid, block, 0, stream>>>(x + off, t, nullptr, nullptr);
            iir_scan<true,  true ><<<grid, block, 0, stream>>>(t, out + off, x + off, alpha);
        }
    } else {
        // No usable scratch: H-pass x -> out, then in-place streaming V-pass.
        const dim3 block(256);
        iir_scan<false, false><<<dim3(4 * 1024), block, 0, stream>>>(x, out, nullptr, nullptr);
        iir_vpass_inplace<<<dim3(256), block, 0, stream>>>(out, x, alpha);
    }
}

// Round 4
// 597.937 us; speedup vs baseline: 1.0139x; 1.0139x over previous
//
#include <hip/hip_runtime.h>

// IIR2DResidual: separable bidirectional first-order IIR (a = 0.5, mirror border)
// along W then H on (N=4, H=512, W=512, C=64) fp32 channels-last, then
// out = x + sigmoid(alpha[c]) * (y - x).
//
// R5 theory (post-mortem of R0-R4): all rounds plateaued at 3.0-3.6 TB/s
// because the compiler SINKS the window loads into the scan loop (VGPR=80 =
// exactly the backward live set), serializing each wave into ~48 dependent
// HBM accesses. Measured rate == occupancy x 1-outstanding-load x 512 B /
// 375 ns latency == 3.0 TB/s. Fix: __builtin_amdgcn_sched_barrier(0) between
// the load loop and the scan -> all 48 loads issued up front (48 outstanding
// per wave), latency fully hidden, pass becomes BW-bound.
//
// Lane map (R4): lane = channel pair (lane&31)*2 of line (lane>>5); wave
// covers 2 lines x 64 channels -> every global op is 2x256B (H) or 512B (V)
// dense. Window held as TWO SCALAR float arrays (vector-elem arrays get
// demoted to scratch, R2/R3 evidence).
//
// Chunking: T=32 outputs, K=8 warm-up halo (0.5^8 ~ 4e-3; measured absmax
// 1.6e-2 vs threshold 6.6e-2). Mirror init exact at w0=0 (warm-up predicated
// off); right edge holds yf[L-1] as fixpoint so the unconditional backward
// warm-up is exact.
//
// XCD swizzle: chunk-adjacent logical blocks land on the same XCD's L2 so
// halo re-reads hit (bijective; grid % 8 == 0 always).
//
// ws robustness: process images in groups sized to fit ws; if ws can't hold
// one image (64 MiB), fall back to in-place V-pass (no scratch needed).

typedef float f2 __attribute__((ext_vector_type(2)));

constexpr int Tc   = 32;            // output chunk per wave
constexpr int Kc   = 8;             // warm-up halo
constexpr int WIN  = Tc + 2 * Kc;   // 48 positions -> 96 scalar floats/lane
constexpr int L    = 512;           // scan length (H == W == 512)
constexpr int C    = 64;
constexpr int W    = 512;
constexpr int H    = 512;
constexpr int CHUNKS = L / Tc;      // 16

template<bool VERT, bool COMBINE>
__global__ __launch_bounds__(256)
void iir_scan(const float* __restrict__ in, float* __restrict__ out,
              const float* __restrict__ xres, const float* __restrict__ alpha)
{
    // --- XCD-aware bijective block swizzle (gridDim.x % 8 == 0 always) ---
    const int nb8 = (int)gridDim.x >> 3;
    const int bid = (int)blockIdx.x;
    const int lb  = (bid & 7) * nb8 + (bid >> 3);   // logical block id

    const int lane = threadIdx.x & 63;
    const int sub  = lane >> 5;          // which of 2 lines this lane serves
    const int c0   = (lane & 31) << 1;   // channel pair
    const int gw   = lb * 4 + (threadIdx.x >> 6);   // logical wave id
    const int lg   = gw >> 4;            // line-pair id (CHUNKS=16 chunks each)
    const int w0   = (gw & (CHUNKS - 1)) * Tc;

    const int n = lg >> 8;               // image index within launch group
    const int r = ((lg & 255) << 1) + sub;

    int base, stride;
    if (VERT) {
        // r = w; scan over h. One load instr = 2 adjacent w -> 512 B contiguous.
        base   = (n * H * W + r) * C + c0;
        stride = W * C;
    } else {
        // r = h; scan over w. One load instr = 2 rows x 256 B dense segments.
        base   = (n * H + r) * (W * C) + c0;
        stride = C;
    }
    const float* __restrict__ p = in + base;

    // Scalar window arrays (register-resident; see header comment).
    float va[WIN], vb[WIN];

    // --- load window (edge-clamped), 8 B/lane dwordx2, ALL issued up front ---
#pragma unroll
    for (int j = 0; j < WIN; ++j) {
        int w = w0 - Kc + j;
        w = min(max(w, 0), L - 1);
        const f2 t = *(const f2*)(p + w * stride);
        va[j] = t.x;
        vb[j] = t.y;
    }
    // Forbid the scheduler from sinking loads into the scan (the R0-R4
    // 3 TB/s plateau was MLP=1 per wave; this keeps 48 loads in flight).
    __builtin_amdgcn_sched_barrier(0);

    // --- forward scan: yf[t] = 0.5*x[t] + 0.5*yf[t-1], mirror init ---
    float ca = va[0], cb = vb[0];        // = x[0] when w0 == 0 (exact mirror)
#pragma unroll
    for (int j = 0; j < WIN; ++j) {
        const int w = w0 - Kc + j;
        if (w >= 0 && w < L) {           // wave-uniform predicate
            ca = 0.5f * va[j] + 0.5f * ca;
            cb = 0.5f * vb[j] + 0.5f * cb;
        }
        va[j] = ca;                      // w >= L: hold yf[L-1] (fixpoint)
        vb[j] = cb;
    }

    // --- backward scan: yb[t] = 0.5*yf[t] + 0.5*yb[t+1] ---
    float c2a = va[WIN - 1], c2b = vb[WIN - 1];
#pragma unroll
    for (int j = WIN - 1; j >= Kc; --j) {
        c2a = 0.5f * va[j] + 0.5f * c2a;
        c2b = 0.5f * vb[j] + 0.5f * c2b;
        va[j] = c2a;
        vb[j] = c2b;
    }

    // --- store output region [w0, w0+Tc), 8 B/lane dwordx2 ---
    if (COMBINE) {
        const f2 av = *(const f2*)(alpha + c0);
        const float mixa = 1.0f / (1.0f + __expf(-av.x));
        const float mixb = 1.0f / (1.0f + __expf(-av.y));
#pragma unroll
        for (int j = Kc; j < Kc + Tc; ++j) {
            const int idx = base + (w0 + (j - Kc)) * stride;
            const f2 xv = *(const f2*)(xres + idx);
            f2 o;
            o.x = xv.x + mixa * (va[j] - xv.x);
            o.y = xv.y + mixb * (vb[j] - xv.y);
            *(f2*)(out + idx) = o;
        }
    } else {
#pragma unroll
        for (int j = Kc; j < Kc + Tc; ++j) {
            const int idx = base + (w0 + (j - Kc)) * stride;
            f2 o;
            o.x = va[j];
            o.y = vb[j];
            *(f2*)(out + idx) = o;
        }
    }
}

// Emergency V-pass when ws can't hold even one image: in-place on y (the
// H-pass result already in d_out). One wave owns 2 (n,w) lines x 32 channel
// pairs -> reads/writes only its own indices, race-free, zero scratch.
__global__ __launch_bounds__(256)
void iir_vpass_inplace(float* __restrict__ y, const float* __restrict__ xres,
                       const float* __restrict__ alpha)
{
    const int lane = threadIdx.x & 63;
    const int sub  = lane >> 5;
    const int c0   = (lane & 31) << 1;
    const int lg   = blockIdx.x * 4 + (threadIdx.x >> 6);  // [0, N*W/2)
    const int n = lg >> 8;
    const int w = ((lg & 255) << 1) + sub;
    const int base   = (n * H * W + w) * C + c0;
    const int stride = W * C;

    // forward, in place
    f2 carry = *(const f2*)(y + base);   // mirror init
    for (int h = 0; h < H; ++h) {
        const int idx = base + h * stride;
        f2 cur = *(const f2*)(y + idx);
        carry = 0.5f * cur + 0.5f * carry;
        *(f2*)(y + idx) = carry;
    }
    // backward + residual, in place
    const f2 av = *(const f2*)(alpha + c0);
    f2 mix;
#pragma unroll
    for (int q = 0; q < 2; ++q)
        mix[q] = 1.0f / (1.0f + __expf(-av[q]));
    f2 c2 = *(const f2*)(y + base + (H - 1) * stride);
    for (int h = H - 1; h >= 0; --h) {
        const int idx = base + h * stride;
        f2 cur = *(const f2*)(y + idx);
        c2 = 0.5f * cur + 0.5f * c2;
        const f2 xv = *(const f2*)(xres + idx);
        *(f2*)(y + idx) = xv + mix * (c2 - xv);
    }
}

extern "C" void kernel_launch(void* const* d_in, const int* in_sizes, int n_in,
                              void* d_out, int out_size, void* d_ws, size_t ws_size,
                              hipStream_t stream) {
    const float* x     = (const float*)d_in[0];
    const float* alpha = (const float*)d_in[1];
    float* out = (float*)d_out;
    float* t   = (float*)d_ws;

    const size_t imgElems = (size_t)H * W * C;          // 16,777,216
    const size_t imgBytes = imgElems * sizeof(float);   // 64 MiB
    const int    N        = 4;

    int g = (int)(ws_size / imgBytes);   // images that fit in ws
    if (g > N) g = N;

    if (g >= 1) {
        // Process images in groups of g: H-pass (x->ws), V-pass+combine (ws->out).
        for (int i0 = 0; i0 < N; i0 += g) {
            const int ni = (i0 + g <= N) ? g : (N - i0);
            const size_t off = (size_t)i0 * imgElems;
            // waves = ni*(512/2) line-pairs * 16 chunks; 4 waves/block
            // blocks = ni*1024 (always % 8 == 0 -> swizzle bijective)
            const dim3 grid((unsigned)(ni * 1024)), block(256);
            iir_scan<false, false><<<grid, block, 0, stream>>>(x + off, t, nullptr, nullptr);
            iir_scan<true,  true ><<<grid, block, 0, stream>>>(t, out + off, x + off, alpha);
        }
    } else {
        // No usable scratch: H-pass x -> out, then in-place streaming V-pass.
        const dim3 block(256);
        iir_scan<false, false><<<dim3(4 * 1024), block, 0, stream>>>(x, out, nullptr, nullptr);
        iir_vpass_inplace<<<dim3(256), block, 0, stream>>>(out, x, alpha);
    }
}